// Round 22
// baseline (469.065 us; speedup 1.0000x reference)
//
#include <hip/hip_runtime.h>
#include <hip/hip_bf16.h>
#include <math.h>
#include <stdint.h>
#include <stddef.h>

typedef short short8 __attribute__((ext_vector_type(8)));   // 8 x bf16 fragment
typedef float f32x4 __attribute__((ext_vector_type(4)));

// DCT basis (P=3): rows {CA,CA,CA},{CB,0,-CB},{CC,CD,CC}
#define CA 0.57735026918962576f
#define CB 0.70710678118654752f
#define CC 0.40824829046386302f
#define CD -0.81649658092772603f

#define NKT 24            // K-tiles of 32
#define NG 6              // staging groups (4 K-tiles each)
#define NWIN 7744
#define NBLKM 1549        // ceil(7744 / 5)
#define NWG3 (NBLKM * 3)  // 4647 blocks
#define AROWB 80          // A-tile LDS row: 64 B real + 16 B pad
#define AKTLB (48 * AROWB)             // 3840 B per ktl slab
#define ABUFB (4 * AKTLB)              // 15360 B per A buffer (dbuf = 30720)
#define EPSTR 68          // epilogue scratch row stride in f16 (136 B)
#define EPWVB 3680        // per-wave scratch: 27 rows * 68 f16
#define LDS_TOTAL 30720   // A dbuf; epilogue (4 waves * 3680) overlays
#define W1H_BYTES (24ull * 768 * 32 * 2)   // 1179648

// f32 -> bf16 RNE via native cvt (1 op)
static __device__ __forceinline__ unsigned short f2bf(float x) {
  __hip_bfloat16 h = __float2bfloat16(x);
  return __builtin_bit_cast(unsigned short, h);
}

// clamp-free tanh GELU (R14/R15-verified): correct limits at +-inf, ~11 ops.
static __device__ __forceinline__ float gelu_fast(float v) {
  float v2 = v * v;
  float inner = fmaf(0.044715f * v2, v, v);        // v + c*v^3
  float z = 0.7978845608028654f * inner;           // sqrt(2/pi)*inner
  float e = __expf(2.f * z);
  float th = 1.f - 2.f * __builtin_amdgcn_rcpf(e + 1.f);
  return 0.5f * v * (1.f + th);
}

// ---------------------------------------------------------------------------
// Kernel 0: W1 f32 [o][i] -> bf16 packed [kt][n][32] (64 B rows, no pad).
// ---------------------------------------------------------------------------
__global__ __launch_bounds__(256) void w1conv(const float* __restrict__ W1,
                                              unsigned short* __restrict__ W1h) {
  const int id = blockIdx.x * 256 + threadIdx.x;   // 24*768
  const int kt = id / 768;
  const int n = id - kt * 768;
  const float* src = W1 + (size_t)n * 768 + kt * 32;
  unsigned short* dst = W1h + ((size_t)kt * 768 + n) * 32;
#pragma unroll
  for (int i = 0; i < 4; ++i) {
    f32x4 v0 = *(const f32x4*)(src + i * 8);
    f32x4 v1 = *(const f32x4*)(src + i * 8 + 4);
    short8 s;
#pragma unroll
    for (int j = 0; j < 4; ++j) {
      s[j] = (short)f2bf(v0[j]);
      s[j + 4] = (short)f2bf(v1[j]);
    }
    *(short8*)(dst + i * 8) = s;
  }
}

// ---------------------------------------------------------------------------
// Main kernel (R22 = R21 + (256,5) occupancy probe):
//   Register-slot law (this session): arch-VGPR cap = 256/launch_bounds_arg.
//   (256,4) = cap 64, using 60 + 48 acc = 108 unified -> exactly 4 waves/SIMD
//   (432/512). (256,5) caps arch at 51: compiler shaves ~9 regs -> 5 blocks/CU
//   = 20 waves (+25% TLP), the single biggest proven lever (R12->R13).
//   TRIPWIRE: WRITE_SIZE >= ~300 MB = hot-loop spill -> revert to R21.
//   Everything else verbatim R21 (the 183 us optimum):
//   - fused DCT staging, dbuf, 1 barrier/group; direct per-phase B loads
//   - T5 setprio(1) around the 12-MFMA cluster (kept: neutral-to-positive)
//   - m204 bijective XCD swizzle (FETCH ~113 MB)
//   - per-wave-private f16[27][68] epilogue, full-line 256 B NT stores
// ---------------------------------------------------------------------------
template <bool USE_WS>
__global__ __launch_bounds__(256, 5) void fused_kernel(
    const float* __restrict__ f, const float* __restrict__ W1,
    const unsigned short* __restrict__ W1h, const float* __restrict__ b1,
    float* __restrict__ out) {
  __shared__ alignas(16) unsigned char smem[LDS_TOTAL];

  // m204 bijective XCD remap: contiguous logical range per XCD so the 3
  // nt-siblings (bid = mblk*3 + ng) land on the same XCD's L2.
  int bid = blockIdx.x;
  {
    const int x = bid & 7, loc = bid >> 3;
    const int q = NWG3 / 8, r = NWG3 & 7;          // 580, 7
    bid = (x < r ? x * (q + 1) : r * (q + 1) + (x - r) * q) + loc;
  }
  const int mblk = bid / 3;
  const int ng = bid - mblk * 3;
  const int n0 = ng * 256;
  const int tid = threadIdx.x;
  const int wv = tid >> 6;           // 0..3
  const int lane = tid & 63;
  const int lrow = lane & 15;
  const int kgrp = lane >> 4;        // 0..3

  // ---- staging unit: (window sw=tid>>5, feature sk=tid&31); 160 active ----
  const int sk = tid & 31;
  const int sw = tid >> 5;           // 0..7 (>=5 -> inactive)
  const bool sact = (sw < 5);

  int sgw = mblk * 5 + (sact ? sw : 0);
  if (sgw > NWIN - 1) sgw = NWIN - 1;
  const int sib = sgw / 484;
  const int srem = sgw - sib * 484;
  const int sbh = srem / 22;
  const int sbw = srem - sbh * 22;
  const float* fbase = f + (size_t)sib * 64 * 64 * 768 + sk;
  int ho[3], wo[3];
#pragma unroll
  for (int p = 0; p < 3; ++p) {
    int h = sbh * 3 + p; h = h > 63 ? 63 : h;   // edge pad == clamp
    ho[p] = h * 64 * 768;
    int w = sbw * 3 + p; w = w > 63 ? 63 : w;
    wo[p] = w * 768;
  }
  const unsigned awr = (unsigned)(sw * 9) * AROWB + (unsigned)sk * 2;

  // ---- B fragment base (this wave's cols, this lane's 8-k slice) ----
  const unsigned short* pbW = W1h + ((size_t)(n0 + wv * 64 + lrow)) * 32 + kgrp * 8;
  const float* pbF = W1 + ((size_t)(n0 + wv * 64 + lrow)) * 768 + kgrp * 8;

  f32x4 acc[12];                     // [rf*4 + cf]
#pragma unroll
  for (int i = 0; i < 12; ++i) acc[i] = (f32x4){0.f, 0.f, 0.f, 0.f};

  float xr[9];                       // one ktl slice of 9 pixels
  auto loadF1 = [&](int g, int sktl) {
    const int fo = g * 128 + sktl * 32;
#pragma unroll
    for (int p = 0; p < 3; ++p)
#pragma unroll
      for (int q = 0; q < 3; ++q)
        xr[p * 3 + q] = fbase[ho[p] + wo[q] + fo];
  };
  auto dct1 = [&](unsigned abuf, int sktl) {
    const unsigned base = abuf + (unsigned)(sktl * AKTLB) + awr;
    float s[3][3];
#pragma unroll
    for (int p = 0; p < 3; ++p) {
      const float tt = xr[p * 3] + xr[p * 3 + 2];
      s[p][0] = CA * (tt + xr[p * 3 + 1]);
      s[p][1] = CB * (xr[p * 3] - xr[p * 3 + 2]);
      s[p][2] = CC * tt + CD * xr[p * 3 + 1];
    }
#pragma unroll
    for (int c = 0; c < 3; ++c) {
      const float tt = s[0][c] + s[2][c];
      *(unsigned short*)(smem + base + (unsigned)c * AROWB) = f2bf(CA * (tt + s[1][c]));
      *(unsigned short*)(smem + base + (unsigned)(3 + c) * AROWB) = f2bf(CB * (s[0][c] - s[2][c]));
      *(unsigned short*)(smem + base + (unsigned)(6 + c) * AROWB) = f2bf(CC * tt + CD * s[1][c]);
    }
  };

  short8 ba0, ba1, ba2, ba3;
  auto loadB = [&](int kt) {
    if (USE_WS) {
      ba0 = *(const short8*)(pbW + ((size_t)kt * 768 + 0) * 32);
      ba1 = *(const short8*)(pbW + ((size_t)kt * 768 + 16) * 32);
      ba2 = *(const short8*)(pbW + ((size_t)kt * 768 + 32) * 32);
      ba3 = *(const short8*)(pbW + ((size_t)kt * 768 + 48) * 32);
    } else {
#pragma unroll
      for (int cf = 0; cf < 4; ++cf) {
        const float* p = pbF + (size_t)(cf * 16) * 768 + kt * 32;
        f32x4 v0 = *(const f32x4*)(p);
        f32x4 v1 = *(const f32x4*)(p + 4);
        short8 s;
#pragma unroll
        for (int j = 0; j < 4; ++j) {
          s[j] = (short)f2bf(v0[j]);
          s[j + 4] = (short)f2bf(v1[j]);
        }
        if (cf == 0) ba0 = s; else if (cf == 1) ba1 = s;
        else if (cf == 2) ba2 = s; else ba3 = s;
      }
    }
  };

  // ---- prologue: stage group 0 (4 ktl sub-passes) into buffer 0 ----
  if (sact) {
#pragma unroll
    for (int sktl = 0; sktl < 4; ++sktl) {
      loadF1(0, sktl);
      dct1(0u, sktl);
    }
  }
  __syncthreads();

  // ---- main loop: 6 groups, ONE barrier each; per ktl phase:
  //      {issue next-group f loads} {load B} {ds_read A} {12 MFMA} {dct+write}
#pragma unroll 1
  for (int g = 0; g < NG; ++g) {
    const unsigned cur = (g & 1) ? (unsigned)ABUFB : 0u;
    const unsigned nxt = cur ^ (unsigned)ABUFB;
    const bool more = (g + 1 < NG);
#pragma unroll
    for (int ktl = 0; ktl < 4; ++ktl) {
      if (more && sact) loadF1(g + 1, ktl);   // f latency hides under phase
      loadB(g * 4 + ktl);
      const unsigned ab = cur + (unsigned)(ktl * AKTLB) + (unsigned)kgrp * 16;
      short8 af0 = *(const short8*)(smem + ab + (unsigned)(0 * 16 + lrow) * AROWB);
      short8 af1 = *(const short8*)(smem + ab + (unsigned)(1 * 16 + lrow) * AROWB);
      short8 af2 = *(const short8*)(smem + ab + (unsigned)(2 * 16 + lrow) * AROWB);
      __builtin_amdgcn_s_setprio(1);          // T5: favor MFMA-issuing wave
      acc[0] = __builtin_amdgcn_mfma_f32_16x16x32_bf16(af0, ba0, acc[0], 0, 0, 0);
      acc[1] = __builtin_amdgcn_mfma_f32_16x16x32_bf16(af0, ba1, acc[1], 0, 0, 0);
      acc[2] = __builtin_amdgcn_mfma_f32_16x16x32_bf16(af0, ba2, acc[2], 0, 0, 0);
      acc[3] = __builtin_amdgcn_mfma_f32_16x16x32_bf16(af0, ba3, acc[3], 0, 0, 0);
      acc[4] = __builtin_amdgcn_mfma_f32_16x16x32_bf16(af1, ba0, acc[4], 0, 0, 0);
      acc[5] = __builtin_amdgcn_mfma_f32_16x16x32_bf16(af1, ba1, acc[5], 0, 0, 0);
      acc[6] = __builtin_amdgcn_mfma_f32_16x16x32_bf16(af1, ba2, acc[6], 0, 0, 0);
      acc[7] = __builtin_amdgcn_mfma_f32_16x16x32_bf16(af1, ba3, acc[7], 0, 0, 0);
      acc[8] = __builtin_amdgcn_mfma_f32_16x16x32_bf16(af2, ba0, acc[8], 0, 0, 0);
      acc[9] = __builtin_amdgcn_mfma_f32_16x16x32_bf16(af2, ba1, acc[9], 0, 0, 0);
      acc[10] = __builtin_amdgcn_mfma_f32_16x16x32_bf16(af2, ba2, acc[10], 0, 0, 0);
      acc[11] = __builtin_amdgcn_mfma_f32_16x16x32_bf16(af2, ba3, acc[11], 0, 0, 0);
      __builtin_amdgcn_s_setprio(0);
      if (more && sact) dct1(nxt, ktl);       // write next buffer (no hazard)
    }
    __syncthreads();                 // last one also fences epilogue reuse
  }

  // ---- epilogue: 2 same-wave passes over PRIVATE f16[27][68] scratch ----
  _Float16* ep = (_Float16*)(smem + wv * EPWVB);
  float bias[4];
#pragma unroll
  for (int cf = 0; cf < 4; ++cf) bias[cf] = b1[n0 + wv * 64 + cf * 16 + lrow];
  const float Cm[3][3] = {{CA, CA, CA}, {CB, 0.f, -CB}, {CC, CD, CC}};

#pragma unroll
  for (int ps = 0; ps < 2; ++ps) {
    const int rowbase = ps * 27;
    const int nrows = ps ? 18 : 27;
    const int nw = ps ? 2 : 3;
#pragma unroll
    for (int rf = 0; rf < 3; ++rf)
#pragma unroll
      for (int cf = 0; cf < 4; ++cf)
#pragma unroll
        for (int j = 0; j < 4; ++j) {
          const int r = rf * 16 + kgrp * 4 + j;   // C/D: row=(lane>>4)*4+reg
          const int lr = r - rowbase;
          if (lr >= 0 && lr < nrows) {
            const float v = acc[rf * 4 + cf][j] + bias[cf];
            ep[lr * EPSTR + cf * 16 + lrow] = (_Float16)gelu_fast(v);
          }
        }
#pragma unroll 1
    for (int w = 0; w < nw; ++w) {
      const int gw = mblk * 5 + ps * 3 + w;
      if (gw >= NWIN) break;               // uniform per block
      const int ib = gw / 484;
      const int rem = gw - ib * 484;
      const int bh = rem / 22;
      const int bw = rem - bh * 22;
      float y[3][3];
#pragma unroll
      for (int a = 0; a < 3; ++a)
#pragma unroll
        for (int c = 0; c < 3; ++c)
          y[a][c] = (float)ep[(w * 9 + a * 3 + c) * EPSTR + lane];
      float vt[3][3];                      // vt[a][q] = sum_c y[a][c]*Cm[c][q]
#pragma unroll
      for (int a = 0; a < 3; ++a)
#pragma unroll
        for (int q = 0; q < 3; ++q)
          vt[a][q] = y[a][0] * Cm[0][q] + y[a][1] * Cm[1][q] + y[a][2] * Cm[2][q];
#pragma unroll
      for (int p = 0; p < 3; ++p) {
        const int h = bh * 3 + p;
        if (h >= 64) continue;             // crop (uniform per block)
#pragma unroll
        for (int q = 0; q < 3; ++q) {
          const int ww = bw * 3 + q;
          if (ww >= 64) continue;          // crop
          const float o = Cm[0][p] * vt[0][q] + Cm[1][p] * vt[1][q] + Cm[2][p] * vt[2][q];
          __builtin_nontemporal_store(
              o, out + ((((size_t)ib * 64 + h) * 64 + ww) * 768 + n0 + wv * 64 + lane));
        }
      }
    }
  }
}

// ---------------------------------------------------------------------------
extern "C" void kernel_launch(void* const* d_in, const int* in_sizes, int n_in,
                              void* d_out, int out_size, void* d_ws, size_t ws_size,
                              hipStream_t stream) {
  const float* f  = (const float*)d_in[0];
  const float* W1 = (const float*)d_in[1];
  const float* b1 = (const float*)d_in[2];
  float* out = (float*)d_out;

  if (ws_size >= W1H_BYTES && d_ws != nullptr) {
    unsigned short* W1h = (unsigned short*)d_ws;
    w1conv<<<dim3(72), dim3(256), 0, stream>>>(W1, W1h);
    fused_kernel<true><<<dim3(NWG3), dim3(256), 0, stream>>>(f, W1, W1h, b1, out);
  } else {
    fused_kernel<false><<<dim3(NWG3), dim3(256), 0, stream>>>(f, W1, nullptr, b1, out);
  }
}

// Round 23
// 180.457 us; speedup vs baseline: 2.5993x; 2.5993x over previous
//
#include <hip/hip_runtime.h>
#include <hip/hip_bf16.h>
#include <math.h>
#include <stdint.h>
#include <stddef.h>

typedef short short8 __attribute__((ext_vector_type(8)));   // 8 x bf16 fragment
typedef float f32x4 __attribute__((ext_vector_type(4)));

// DCT basis (P=3): rows {CA,CA,CA},{CB,0,-CB},{CC,CD,CC}
#define CA 0.57735026918962576f
#define CB 0.70710678118654752f
#define CC 0.40824829046386302f
#define CD -0.81649658092772603f

#define NKT 24            // K-tiles of 32
#define NG 6              // staging groups (4 K-tiles each)
#define NWIN 7744
#define NBLKM 1549        // ceil(7744 / 5)
#define NWG3 (NBLKM * 3)  // 4647 blocks
#define AROWB 80          // A-tile LDS row: 64 B real + 16 B pad
#define AKTLB (48 * AROWB)             // 3840 B per ktl slab
#define ABUFB (4 * AKTLB)              // 15360 B per A buffer (dbuf = 30720)
#define EPSTR 68          // epilogue scratch row stride in f16 (136 B)
#define EPWVB 3680        // per-wave scratch: 27 rows * 68 f16
#define LDS_TOTAL 30720   // A dbuf; epilogue (4 waves * 3680) overlays
#define W1H_BYTES (24ull * 768 * 32 * 2)   // 1179648

// f32 -> bf16 RNE via native cvt (1 op)
static __device__ __forceinline__ unsigned short f2bf(float x) {
  __hip_bfloat16 h = __float2bfloat16(x);
  return __builtin_bit_cast(unsigned short, h);
}

// clamp-free tanh GELU (R14/R15-verified): correct limits at +-inf, ~11 ops.
static __device__ __forceinline__ float gelu_fast(float v) {
  float v2 = v * v;
  float inner = fmaf(0.044715f * v2, v, v);        // v + c*v^3
  float z = 0.7978845608028654f * inner;           // sqrt(2/pi)*inner
  float e = __expf(2.f * z);
  float th = 1.f - 2.f * __builtin_amdgcn_rcpf(e + 1.f);
  return 0.5f * v * (1.f + th);
}

// ---------------------------------------------------------------------------
// Kernel 0: W1 f32 [o][i] -> bf16 packed [kt][n][32] (64 B rows, no pad).
// ---------------------------------------------------------------------------
__global__ __launch_bounds__(256) void w1conv(const float* __restrict__ W1,
                                              unsigned short* __restrict__ W1h) {
  const int id = blockIdx.x * 256 + threadIdx.x;   // 24*768
  const int kt = id / 768;
  const int n = id - kt * 768;
  const float* src = W1 + (size_t)n * 768 + kt * 32;
  unsigned short* dst = W1h + ((size_t)kt * 768 + n) * 32;
#pragma unroll
  for (int i = 0; i < 4; ++i) {
    f32x4 v0 = *(const f32x4*)(src + i * 8);
    f32x4 v1 = *(const f32x4*)(src + i * 8 + 4);
    short8 s;
#pragma unroll
    for (int j = 0; j < 4; ++j) {
      s[j] = (short)f2bf(v0[j]);
      s[j + 4] = (short)f2bf(v1[j]);
    }
    *(short8*)(dst + i * 8) = s;
  }
}

// ---------------------------------------------------------------------------
// Main kernel (R23 = R21 verbatim, the session optimum: 182.96 us).
//   Fused edge-clamped 3x3 DCT + bf16 MFMA GEMM (M=69696,N=768,K=768) +
//   bias + fast-GELU + 3x3 IDCT + crop. Session boundary map:
//   - (256,4) blocks: register-slot law (arch cap = 256/arg); working set
//     108 unified regs/wave = exact 4-wave/SIMD fit. 5th slot spills
//     (R22: WRITE 196MB -> 1.13GB, 2.6x slower); 6-wave blocks strand
//     SIMD slots (R19: occ 42->28%, 1.25x slower).
//   - 1-barrier dbuf K-loop; counted-vmcnt needs full-VMEM-staged redesign
//     (R17 NaN: B-loads force vmcnt(0); 12B gload_lds stride unverified).
//   - WRITE = 1.00x ideal via full-line 256B NT stores (R5: fixed the 27x
//     fragment-store amplification); FETCH 113MB via m204 XCD swizzle.
//   - VALU dedup fails both ways: workspace split +HBM > -VALU (R16);
//     pk-math costs live regs -> spill at the cap (R14).
//   - T5 setprio around MFMA cluster: neutral-to-positive (R21), kept.
// ---------------------------------------------------------------------------
template <bool USE_WS>
__global__ __launch_bounds__(256, 4) void fused_kernel(
    const float* __restrict__ f, const float* __restrict__ W1,
    const unsigned short* __restrict__ W1h, const float* __restrict__ b1,
    float* __restrict__ out) {
  __shared__ alignas(16) unsigned char smem[LDS_TOTAL];

  // m204 bijective XCD remap: contiguous logical range per XCD so the 3
  // nt-siblings (bid = mblk*3 + ng) land on the same XCD's L2.
  int bid = blockIdx.x;
  {
    const int x = bid & 7, loc = bid >> 3;
    const int q = NWG3 / 8, r = NWG3 & 7;          // 580, 7
    bid = (x < r ? x * (q + 1) : r * (q + 1) + (x - r) * q) + loc;
  }
  const int mblk = bid / 3;
  const int ng = bid - mblk * 3;
  const int n0 = ng * 256;
  const int tid = threadIdx.x;
  const int wv = tid >> 6;           // 0..3
  const int lane = tid & 63;
  const int lrow = lane & 15;
  const int kgrp = lane >> 4;        // 0..3

  // ---- staging unit: (window sw=tid>>5, feature sk=tid&31); 160 active ----
  const int sk = tid & 31;
  const int sw = tid >> 5;           // 0..7 (>=5 -> inactive)
  const bool sact = (sw < 5);

  int sgw = mblk * 5 + (sact ? sw : 0);
  if (sgw > NWIN - 1) sgw = NWIN - 1;
  const int sib = sgw / 484;
  const int srem = sgw - sib * 484;
  const int sbh = srem / 22;
  const int sbw = srem - sbh * 22;
  const float* fbase = f + (size_t)sib * 64 * 64 * 768 + sk;
  int ho[3], wo[3];
#pragma unroll
  for (int p = 0; p < 3; ++p) {
    int h = sbh * 3 + p; h = h > 63 ? 63 : h;   // edge pad == clamp
    ho[p] = h * 64 * 768;
    int w = sbw * 3 + p; w = w > 63 ? 63 : w;
    wo[p] = w * 768;
  }
  const unsigned awr = (unsigned)(sw * 9) * AROWB + (unsigned)sk * 2;

  // ---- B fragment base (this wave's cols, this lane's 8-k slice) ----
  const unsigned short* pbW = W1h + ((size_t)(n0 + wv * 64 + lrow)) * 32 + kgrp * 8;
  const float* pbF = W1 + ((size_t)(n0 + wv * 64 + lrow)) * 768 + kgrp * 8;

  f32x4 acc[12];                     // [rf*4 + cf]
#pragma unroll
  for (int i = 0; i < 12; ++i) acc[i] = (f32x4){0.f, 0.f, 0.f, 0.f};

  float xr[9];                       // one ktl slice of 9 pixels
  auto loadF1 = [&](int g, int sktl) {
    const int fo = g * 128 + sktl * 32;
#pragma unroll
    for (int p = 0; p < 3; ++p)
#pragma unroll
      for (int q = 0; q < 3; ++q)
        xr[p * 3 + q] = fbase[ho[p] + wo[q] + fo];
  };
  auto dct1 = [&](unsigned abuf, int sktl) {
    const unsigned base = abuf + (unsigned)(sktl * AKTLB) + awr;
    float s[3][3];
#pragma unroll
    for (int p = 0; p < 3; ++p) {
      const float tt = xr[p * 3] + xr[p * 3 + 2];
      s[p][0] = CA * (tt + xr[p * 3 + 1]);
      s[p][1] = CB * (xr[p * 3] - xr[p * 3 + 2]);
      s[p][2] = CC * tt + CD * xr[p * 3 + 1];
    }
#pragma unroll
    for (int c = 0; c < 3; ++c) {
      const float tt = s[0][c] + s[2][c];
      *(unsigned short*)(smem + base + (unsigned)c * AROWB) = f2bf(CA * (tt + s[1][c]));
      *(unsigned short*)(smem + base + (unsigned)(3 + c) * AROWB) = f2bf(CB * (s[0][c] - s[2][c]));
      *(unsigned short*)(smem + base + (unsigned)(6 + c) * AROWB) = f2bf(CC * tt + CD * s[1][c]);
    }
  };

  short8 ba0, ba1, ba2, ba3;
  auto loadB = [&](int kt) {
    if (USE_WS) {
      ba0 = *(const short8*)(pbW + ((size_t)kt * 768 + 0) * 32);
      ba1 = *(const short8*)(pbW + ((size_t)kt * 768 + 16) * 32);
      ba2 = *(const short8*)(pbW + ((size_t)kt * 768 + 32) * 32);
      ba3 = *(const short8*)(pbW + ((size_t)kt * 768 + 48) * 32);
    } else {
#pragma unroll
      for (int cf = 0; cf < 4; ++cf) {
        const float* p = pbF + (size_t)(cf * 16) * 768 + kt * 32;
        f32x4 v0 = *(const f32x4*)(p);
        f32x4 v1 = *(const f32x4*)(p + 4);
        short8 s;
#pragma unroll
        for (int j = 0; j < 4; ++j) {
          s[j] = (short)f2bf(v0[j]);
          s[j + 4] = (short)f2bf(v1[j]);
        }
        if (cf == 0) ba0 = s; else if (cf == 1) ba1 = s;
        else if (cf == 2) ba2 = s; else ba3 = s;
      }
    }
  };

  // ---- prologue: stage group 0 (4 ktl sub-passes) into buffer 0 ----
  if (sact) {
#pragma unroll
    for (int sktl = 0; sktl < 4; ++sktl) {
      loadF1(0, sktl);
      dct1(0u, sktl);
    }
  }
  __syncthreads();

  // ---- main loop: 6 groups, ONE barrier each; per ktl phase:
  //      {issue next-group f loads} {load B} {ds_read A} {12 MFMA} {dct+write}
#pragma unroll 1
  for (int g = 0; g < NG; ++g) {
    const unsigned cur = (g & 1) ? (unsigned)ABUFB : 0u;
    const unsigned nxt = cur ^ (unsigned)ABUFB;
    const bool more = (g + 1 < NG);
#pragma unroll
    for (int ktl = 0; ktl < 4; ++ktl) {
      if (more && sact) loadF1(g + 1, ktl);   // f latency hides under phase
      loadB(g * 4 + ktl);
      const unsigned ab = cur + (unsigned)(ktl * AKTLB) + (unsigned)kgrp * 16;
      short8 af0 = *(const short8*)(smem + ab + (unsigned)(0 * 16 + lrow) * AROWB);
      short8 af1 = *(const short8*)(smem + ab + (unsigned)(1 * 16 + lrow) * AROWB);
      short8 af2 = *(const short8*)(smem + ab + (unsigned)(2 * 16 + lrow) * AROWB);
      __builtin_amdgcn_s_setprio(1);          // T5: favor MFMA-issuing wave
      acc[0] = __builtin_amdgcn_mfma_f32_16x16x32_bf16(af0, ba0, acc[0], 0, 0, 0);
      acc[1] = __builtin_amdgcn_mfma_f32_16x16x32_bf16(af0, ba1, acc[1], 0, 0, 0);
      acc[2] = __builtin_amdgcn_mfma_f32_16x16x32_bf16(af0, ba2, acc[2], 0, 0, 0);
      acc[3] = __builtin_amdgcn_mfma_f32_16x16x32_bf16(af0, ba3, acc[3], 0, 0, 0);
      acc[4] = __builtin_amdgcn_mfma_f32_16x16x32_bf16(af1, ba0, acc[4], 0, 0, 0);
      acc[5] = __builtin_amdgcn_mfma_f32_16x16x32_bf16(af1, ba1, acc[5], 0, 0, 0);
      acc[6] = __builtin_amdgcn_mfma_f32_16x16x32_bf16(af1, ba2, acc[6], 0, 0, 0);
      acc[7] = __builtin_amdgcn_mfma_f32_16x16x32_bf16(af1, ba3, acc[7], 0, 0, 0);
      acc[8] = __builtin_amdgcn_mfma_f32_16x16x32_bf16(af2, ba0, acc[8], 0, 0, 0);
      acc[9] = __builtin_amdgcn_mfma_f32_16x16x32_bf16(af2, ba1, acc[9], 0, 0, 0);
      acc[10] = __builtin_amdgcn_mfma_f32_16x16x32_bf16(af2, ba2, acc[10], 0, 0, 0);
      acc[11] = __builtin_amdgcn_mfma_f32_16x16x32_bf16(af2, ba3, acc[11], 0, 0, 0);
      __builtin_amdgcn_s_setprio(0);
      if (more && sact) dct1(nxt, ktl);       // write next buffer (no hazard)
    }
    __syncthreads();                 // last one also fences epilogue reuse
  }

  // ---- epilogue: 2 same-wave passes over PRIVATE f16[27][68] scratch ----
  _Float16* ep = (_Float16*)(smem + wv * EPWVB);
  float bias[4];
#pragma unroll
  for (int cf = 0; cf < 4; ++cf) bias[cf] = b1[n0 + wv * 64 + cf * 16 + lrow];
  const float Cm[3][3] = {{CA, CA, CA}, {CB, 0.f, -CB}, {CC, CD, CC}};

#pragma unroll
  for (int ps = 0; ps < 2; ++ps) {
    const int rowbase = ps * 27;
    const int nrows = ps ? 18 : 27;
    const int nw = ps ? 2 : 3;
#pragma unroll
    for (int rf = 0; rf < 3; ++rf)
#pragma unroll
      for (int cf = 0; cf < 4; ++cf)
#pragma unroll
        for (int j = 0; j < 4; ++j) {
          const int r = rf * 16 + kgrp * 4 + j;   // C/D: row=(lane>>4)*4+reg
          const int lr = r - rowbase;
          if (lr >= 0 && lr < nrows) {
            const float v = acc[rf * 4 + cf][j] + bias[cf];
            ep[lr * EPSTR + cf * 16 + lrow] = (_Float16)gelu_fast(v);
          }
        }
#pragma unroll 1
    for (int w = 0; w < nw; ++w) {
      const int gw = mblk * 5 + ps * 3 + w;
      if (gw >= NWIN) break;               // uniform per block
      const int ib = gw / 484;
      const int rem = gw - ib * 484;
      const int bh = rem / 22;
      const int bw = rem - bh * 22;
      float y[3][3];
#pragma unroll
      for (int a = 0; a < 3; ++a)
#pragma unroll
        for (int c = 0; c < 3; ++c)
          y[a][c] = (float)ep[(w * 9 + a * 3 + c) * EPSTR + lane];
      float vt[3][3];                      // vt[a][q] = sum_c y[a][c]*Cm[c][q]
#pragma unroll
      for (int a = 0; a < 3; ++a)
#pragma unroll
        for (int q = 0; q < 3; ++q)
          vt[a][q] = y[a][0] * Cm[0][q] + y[a][1] * Cm[1][q] + y[a][2] * Cm[2][q];
#pragma unroll
      for (int p = 0; p < 3; ++p) {
        const int h = bh * 3 + p;
        if (h >= 64) continue;             // crop (uniform per block)
#pragma unroll
        for (int q = 0; q < 3; ++q) {
          const int ww = bw * 3 + q;
          if (ww >= 64) continue;          // crop
          const float o = Cm[0][p] * vt[0][q] + Cm[1][p] * vt[1][q] + Cm[2][p] * vt[2][q];
          __builtin_nontemporal_store(
              o, out + ((((size_t)ib * 64 + h) * 64 + ww) * 768 + n0 + wv * 64 + lane));
        }
      }
    }
  }
}

// ---------------------------------------------------------------------------
extern "C" void kernel_launch(void* const* d_in, const int* in_sizes, int n_in,
                              void* d_out, int out_size, void* d_ws, size_t ws_size,
                              hipStream_t stream) {
  const float* f  = (const float*)d_in[0];
  const float* W1 = (const float*)d_in[1];
  const float* b1 = (const float*)d_in[2];
  float* out = (float*)d_out;

  if (ws_size >= W1H_BYTES && d_ws != nullptr) {
    unsigned short* W1h = (unsigned short*)d_ws;
    w1conv<<<dim3(72), dim3(256), 0, stream>>>(W1, W1h);
    fused_kernel<true><<<dim3(NWG3), dim3(256), 0, stream>>>(f, W1, W1h, b1, out);
  } else {
    fused_kernel<false><<<dim3(NWG3), dim3(256), 0, stream>>>(f, W1, nullptr, b1, out);
  }
}

// Round 24
// 180.279 us; speedup vs baseline: 2.6019x; 1.0010x over previous
//
#include <hip/hip_runtime.h>
#include <hip/hip_bf16.h>
#include <math.h>
#include <stdint.h>
#include <stddef.h>

typedef short short8 __attribute__((ext_vector_type(8)));   // 8 x bf16 fragment
typedef float f32x4 __attribute__((ext_vector_type(4)));

// DCT basis (P=3): rows {CA,CA,CA},{CB,0,-CB},{CC,CD,CC}
#define CA 0.57735026918962576f
#define CB 0.70710678118654752f
#define CC 0.40824829046386302f
#define CD -0.81649658092772603f

#define NKT 24            // K-tiles of 32
#define NG 6              // staging groups (4 K-tiles each)
#define NWIN 7744
#define NBLKM 1549        // ceil(7744 / 5)
#define NWG3 (NBLKM * 3)  // 4647 blocks
#define AROWB 80          // A-tile LDS row: 64 B real + 16 B pad
#define AKTLB (48 * AROWB)             // 3840 B per ktl slab
#define ABUFB (4 * AKTLB)              // 15360 B per A buffer (dbuf = 30720)
#define EPSTR 68          // epilogue scratch row stride in f16 (136 B)
#define EPWVB 3680        // per-wave scratch: 27 rows * 68 f16
#define LDS_TOTAL 30720   // A dbuf; epilogue (4 waves * 3680) overlays
#define W1H_BYTES (24ull * 768 * 32 * 2)   // 1179648

// f32 -> bf16 RNE via native cvt (1 op)
static __device__ __forceinline__ unsigned short f2bf(float x) {
  __hip_bfloat16 h = __float2bfloat16(x);
  return __builtin_bit_cast(unsigned short, h);
}

// clamp-free tanh GELU (R14/R15-verified): correct limits at +-inf, ~11 ops.
static __device__ __forceinline__ float gelu_fast(float v) {
  float v2 = v * v;
  float inner = fmaf(0.044715f * v2, v, v);        // v + c*v^3
  float z = 0.7978845608028654f * inner;           // sqrt(2/pi)*inner
  float e = __expf(2.f * z);
  float th = 1.f - 2.f * __builtin_amdgcn_rcpf(e + 1.f);
  return 0.5f * v * (1.f + th);
}

// ---------------------------------------------------------------------------
// Kernel 0: W1 f32 [o][i] -> bf16 packed [kt][n][32] (64 B rows, no pad).
// ---------------------------------------------------------------------------
__global__ __launch_bounds__(256) void w1conv(const float* __restrict__ W1,
                                              unsigned short* __restrict__ W1h) {
  const int id = blockIdx.x * 256 + threadIdx.x;   // 24*768
  const int kt = id / 768;
  const int n = id - kt * 768;
  const float* src = W1 + (size_t)n * 768 + kt * 32;
  unsigned short* dst = W1h + ((size_t)kt * 768 + n) * 32;
#pragma unroll
  for (int i = 0; i < 4; ++i) {
    f32x4 v0 = *(const f32x4*)(src + i * 8);
    f32x4 v1 = *(const f32x4*)(src + i * 8 + 4);
    short8 s;
#pragma unroll
    for (int j = 0; j < 4; ++j) {
      s[j] = (short)f2bf(v0[j]);
      s[j + 4] = (short)f2bf(v1[j]);
    }
    *(short8*)(dst + i * 8) = s;
  }
}

// ---------------------------------------------------------------------------
// Main kernel (FINAL = session optimum, confirmed x3: 183.4/183.0/180.5 us).
//   Fused edge-clamped 3x3 DCT + bf16 MFMA GEMM (M=69696,N=768,K=768) +
//   bias + fast-GELU + 3x3 IDCT + crop. Structural ceiling map:
//   - (256,4) blocks: register-slot law (arch cap = 256/arg); working set
//     108 unified regs/wave = exact 4-wave/SIMD fit of the 512-reg file.
//     5th slot spills (R22: WRITE 196MB->1.13GB, 2.6x); 6-wave blocks
//     strand SIMD slots (R19: occ 42->28%, 1.25x).
//   - 1-barrier dbuf K-loop; counted-vmcnt needs B through global_load_lds
//     and B's 64KB/group tile doesn't fit LDS beside A -> path closed.
//   - WRITE = 1.00x ideal via full-line 256B NT stores (R5 fixed the 27x
//     fragment-store amplification); FETCH 113MB via m204 XCD swizzle.
//   - VALU dedup fails both ways: workspace split +HBM > -VALU (R16);
//     pk-math costs live regs -> spill at the cap (R14).
//   - T5 setprio around MFMA cluster: neutral-to-positive (R21), kept.
// ---------------------------------------------------------------------------
template <bool USE_WS>
__global__ __launch_bounds__(256, 4) void fused_kernel(
    const float* __restrict__ f, const float* __restrict__ W1,
    const unsigned short* __restrict__ W1h, const float* __restrict__ b1,
    float* __restrict__ out) {
  __shared__ alignas(16) unsigned char smem[LDS_TOTAL];

  // m204 bijective XCD remap: contiguous logical range per XCD so the 3
  // nt-siblings (bid = mblk*3 + ng) land on the same XCD's L2.
  int bid = blockIdx.x;
  {
    const int x = bid & 7, loc = bid >> 3;
    const int q = NWG3 / 8, r = NWG3 & 7;          // 580, 7
    bid = (x < r ? x * (q + 1) : r * (q + 1) + (x - r) * q) + loc;
  }
  const int mblk = bid / 3;
  const int ng = bid - mblk * 3;
  const int n0 = ng * 256;
  const int tid = threadIdx.x;
  const int wv = tid >> 6;           // 0..3
  const int lane = tid & 63;
  const int lrow = lane & 15;
  const int kgrp = lane >> 4;        // 0..3

  // ---- staging unit: (window sw=tid>>5, feature sk=tid&31); 160 active ----
  const int sk = tid & 31;
  const int sw = tid >> 5;           // 0..7 (>=5 -> inactive)
  const bool sact = (sw < 5);

  int sgw = mblk * 5 + (sact ? sw : 0);
  if (sgw > NWIN - 1) sgw = NWIN - 1;
  const int sib = sgw / 484;
  const int srem = sgw - sib * 484;
  const int sbh = srem / 22;
  const int sbw = srem - sbh * 22;
  const float* fbase = f + (size_t)sib * 64 * 64 * 768 + sk;
  int ho[3], wo[3];
#pragma unroll
  for (int p = 0; p < 3; ++p) {
    int h = sbh * 3 + p; h = h > 63 ? 63 : h;   // edge pad == clamp
    ho[p] = h * 64 * 768;
    int w = sbw * 3 + p; w = w > 63 ? 63 : w;
    wo[p] = w * 768;
  }
  const unsigned awr = (unsigned)(sw * 9) * AROWB + (unsigned)sk * 2;

  // ---- B fragment base (this wave's cols, this lane's 8-k slice) ----
  const unsigned short* pbW = W1h + ((size_t)(n0 + wv * 64 + lrow)) * 32 + kgrp * 8;
  const float* pbF = W1 + ((size_t)(n0 + wv * 64 + lrow)) * 768 + kgrp * 8;

  f32x4 acc[12];                     // [rf*4 + cf]
#pragma unroll
  for (int i = 0; i < 12; ++i) acc[i] = (f32x4){0.f, 0.f, 0.f, 0.f};

  float xr[9];                       // one ktl slice of 9 pixels
  auto loadF1 = [&](int g, int sktl) {
    const int fo = g * 128 + sktl * 32;
#pragma unroll
    for (int p = 0; p < 3; ++p)
#pragma unroll
      for (int q = 0; q < 3; ++q)
        xr[p * 3 + q] = fbase[ho[p] + wo[q] + fo];
  };
  auto dct1 = [&](unsigned abuf, int sktl) {
    const unsigned base = abuf + (unsigned)(sktl * AKTLB) + awr;
    float s[3][3];
#pragma unroll
    for (int p = 0; p < 3; ++p) {
      const float tt = xr[p * 3] + xr[p * 3 + 2];
      s[p][0] = CA * (tt + xr[p * 3 + 1]);
      s[p][1] = CB * (xr[p * 3] - xr[p * 3 + 2]);
      s[p][2] = CC * tt + CD * xr[p * 3 + 1];
    }
#pragma unroll
    for (int c = 0; c < 3; ++c) {
      const float tt = s[0][c] + s[2][c];
      *(unsigned short*)(smem + base + (unsigned)c * AROWB) = f2bf(CA * (tt + s[1][c]));
      *(unsigned short*)(smem + base + (unsigned)(3 + c) * AROWB) = f2bf(CB * (s[0][c] - s[2][c]));
      *(unsigned short*)(smem + base + (unsigned)(6 + c) * AROWB) = f2bf(CC * tt + CD * s[1][c]);
    }
  };

  short8 ba0, ba1, ba2, ba3;
  auto loadB = [&](int kt) {
    if (USE_WS) {
      ba0 = *(const short8*)(pbW + ((size_t)kt * 768 + 0) * 32);
      ba1 = *(const short8*)(pbW + ((size_t)kt * 768 + 16) * 32);
      ba2 = *(const short8*)(pbW + ((size_t)kt * 768 + 32) * 32);
      ba3 = *(const short8*)(pbW + ((size_t)kt * 768 + 48) * 32);
    } else {
#pragma unroll
      for (int cf = 0; cf < 4; ++cf) {
        const float* p = pbF + (size_t)(cf * 16) * 768 + kt * 32;
        f32x4 v0 = *(const f32x4*)(p);
        f32x4 v1 = *(const f32x4*)(p + 4);
        short8 s;
#pragma unroll
        for (int j = 0; j < 4; ++j) {
          s[j] = (short)f2bf(v0[j]);
          s[j + 4] = (short)f2bf(v1[j]);
        }
        if (cf == 0) ba0 = s; else if (cf == 1) ba1 = s;
        else if (cf == 2) ba2 = s; else ba3 = s;
      }
    }
  };

  // ---- prologue: stage group 0 (4 ktl sub-passes) into buffer 0 ----
  if (sact) {
#pragma unroll
    for (int sktl = 0; sktl < 4; ++sktl) {
      loadF1(0, sktl);
      dct1(0u, sktl);
    }
  }
  __syncthreads();

  // ---- main loop: 6 groups, ONE barrier each; per ktl phase:
  //      {issue next-group f loads} {load B} {ds_read A} {12 MFMA} {dct+write}
#pragma unroll 1
  for (int g = 0; g < NG; ++g) {
    const unsigned cur = (g & 1) ? (unsigned)ABUFB : 0u;
    const unsigned nxt = cur ^ (unsigned)ABUFB;
    const bool more = (g + 1 < NG);
#pragma unroll
    for (int ktl = 0; ktl < 4; ++ktl) {
      if (more && sact) loadF1(g + 1, ktl);   // f latency hides under phase
      loadB(g * 4 + ktl);
      const unsigned ab = cur + (unsigned)(ktl * AKTLB) + (unsigned)kgrp * 16;
      short8 af0 = *(const short8*)(smem + ab + (unsigned)(0 * 16 + lrow) * AROWB);
      short8 af1 = *(const short8*)(smem + ab + (unsigned)(1 * 16 + lrow) * AROWB);
      short8 af2 = *(const short8*)(smem + ab + (unsigned)(2 * 16 + lrow) * AROWB);
      __builtin_amdgcn_s_setprio(1);          // T5: favor MFMA-issuing wave
      acc[0] = __builtin_amdgcn_mfma_f32_16x16x32_bf16(af0, ba0, acc[0], 0, 0, 0);
      acc[1] = __builtin_amdgcn_mfma_f32_16x16x32_bf16(af0, ba1, acc[1], 0, 0, 0);
      acc[2] = __builtin_amdgcn_mfma_f32_16x16x32_bf16(af0, ba2, acc[2], 0, 0, 0);
      acc[3] = __builtin_amdgcn_mfma_f32_16x16x32_bf16(af0, ba3, acc[3], 0, 0, 0);
      acc[4] = __builtin_amdgcn_mfma_f32_16x16x32_bf16(af1, ba0, acc[4], 0, 0, 0);
      acc[5] = __builtin_amdgcn_mfma_f32_16x16x32_bf16(af1, ba1, acc[5], 0, 0, 0);
      acc[6] = __builtin_amdgcn_mfma_f32_16x16x32_bf16(af1, ba2, acc[6], 0, 0, 0);
      acc[7] = __builtin_amdgcn_mfma_f32_16x16x32_bf16(af1, ba3, acc[7], 0, 0, 0);
      acc[8] = __builtin_amdgcn_mfma_f32_16x16x32_bf16(af2, ba0, acc[8], 0, 0, 0);
      acc[9] = __builtin_amdgcn_mfma_f32_16x16x32_bf16(af2, ba1, acc[9], 0, 0, 0);
      acc[10] = __builtin_amdgcn_mfma_f32_16x16x32_bf16(af2, ba2, acc[10], 0, 0, 0);
      acc[11] = __builtin_amdgcn_mfma_f32_16x16x32_bf16(af2, ba3, acc[11], 0, 0, 0);
      __builtin_amdgcn_s_setprio(0);
      if (more && sact) dct1(nxt, ktl);       // write next buffer (no hazard)
    }
    __syncthreads();                 // last one also fences epilogue reuse
  }

  // ---- epilogue: 2 same-wave passes over PRIVATE f16[27][68] scratch ----
  _Float16* ep = (_Float16*)(smem + wv * EPWVB);
  float bias[4];
#pragma unroll
  for (int cf = 0; cf < 4; ++cf) bias[cf] = b1[n0 + wv * 64 + cf * 16 + lrow];
  const float Cm[3][3] = {{CA, CA, CA}, {CB, 0.f, -CB}, {CC, CD, CC}};

#pragma unroll
  for (int ps = 0; ps < 2; ++ps) {
    const int rowbase = ps * 27;
    const int nrows = ps ? 18 : 27;
    const int nw = ps ? 2 : 3;
#pragma unroll
    for (int rf = 0; rf < 3; ++rf)
#pragma unroll
      for (int cf = 0; cf < 4; ++cf)
#pragma unroll
        for (int j = 0; j < 4; ++j) {
          const int r = rf * 16 + kgrp * 4 + j;   // C/D: row=(lane>>4)*4+reg
          const int lr = r - rowbase;
          if (lr >= 0 && lr < nrows) {
            const float v = acc[rf * 4 + cf][j] + bias[cf];
            ep[lr * EPSTR + cf * 16 + lrow] = (_Float16)gelu_fast(v);
          }
        }
#pragma unroll 1
    for (int w = 0; w < nw; ++w) {
      const int gw = mblk * 5 + ps * 3 + w;
      if (gw >= NWIN) break;               // uniform per block
      const int ib = gw / 484;
      const int rem = gw - ib * 484;
      const int bh = rem / 22;
      const int bw = rem - bh * 22;
      float y[3][3];
#pragma unroll
      for (int a = 0; a < 3; ++a)
#pragma unroll
        for (int c = 0; c < 3; ++c)
          y[a][c] = (float)ep[(w * 9 + a * 3 + c) * EPSTR + lane];
      float vt[3][3];                      // vt[a][q] = sum_c y[a][c]*Cm[c][q]
#pragma unroll
      for (int a = 0; a < 3; ++a)
#pragma unroll
        for (int q = 0; q < 3; ++q)
          vt[a][q] = y[a][0] * Cm[0][q] + y[a][1] * Cm[1][q] + y[a][2] * Cm[2][q];
#pragma unroll
      for (int p = 0; p < 3; ++p) {
        const int h = bh * 3 + p;
        if (h >= 64) continue;             // crop (uniform per block)
#pragma unroll
        for (int q = 0; q < 3; ++q) {
          const int ww = bw * 3 + q;
          if (ww >= 64) continue;          // crop
          const float o = Cm[0][p] * vt[0][q] + Cm[1][p] * vt[1][q] + Cm[2][p] * vt[2][q];
          __builtin_nontemporal_store(
              o, out + ((((size_t)ib * 64 + h) * 64 + ww) * 768 + n0 + wv * 64 + lane));
        }
      }
    }
  }
}

// ---------------------------------------------------------------------------
extern "C" void kernel_launch(void* const* d_in, const int* in_sizes, int n_in,
                              void* d_out, int out_size, void* d_ws, size_t ws_size,
                              hipStream_t stream) {
  const float* f  = (const float*)d_in[0];
  const float* W1 = (const float*)d_in[1];
  const float* b1 = (const float*)d_in[2];
  float* out = (float*)d_out;

  if (ws_size >= W1H_BYTES && d_ws != nullptr) {
    unsigned short* W1h = (unsigned short*)d_ws;
    w1conv<<<dim3(72), dim3(256), 0, stream>>>(W1, W1h);
    fused_kernel<true><<<dim3(NWG3), dim3(256), 0, stream>>>(f, W1, W1h, b1, out);
  } else {
    fused_kernel<false><<<dim3(NWG3), dim3(256), 0, stream>>>(f, W1, nullptr, b1, out);
  }
}